// Round 1
// baseline (191.898 us; speedup 1.0000x reference)
//
#include <hip/hip_runtime.h>
#include <math.h>

// Problem constants
#define B_  8
#define T_  128    // T1 == T2 == 128
#define C_  256
#define KP  768    // K dim of GEMM: 3*C (kh x ci) or (kw x ci)
#define NQ  768    // N dim of GEMM: C*3 (o x kw) or (o x kh)

__device__ __forceinline__ float gelu_exact(float x) {
    return 0.5f * x * (1.0f + erff(x * 0.70710678118654752f));
}

// Y[side][b][m][q] = sum_p L[m][p] * R[p][q]
// side 0: L[m][p] = x1pad[b, m+kh-1, ci]   (p = kh*256+ci), R[p][q] = W[o,ci,kh,kw]      (q = o*3+kw)
// side 1: L[m][p] = x2pad[b, m+kw-1, ci]   (p = kw*256+ci), R[p][q] = W[o,256+ci,kh,kw]  (q = o*3+kh)
__global__ __launch_bounds__(256) void tc_gemm(
    const float* __restrict__ x1, const float* __restrict__ x2,
    const float* __restrict__ W, float* __restrict__ Y)
{
    const int tile_n = blockIdx.x;   // 0..11  (N = 768 / 64)
    const int tile_m = blockIdx.y;   // 0..1   (M = 128 / 64)
    const int b      = blockIdx.z >> 1;
    const int side   = blockIdx.z & 1;

    const float* __restrict__ Xb = (side ? x2 : x1) + (size_t)b * T_ * C_;

    __shared__ float As[16][68];   // [k][m], padded: write banks (4k+m)%32 -> 2-way max
    __shared__ float Bs[16][64];   // [k][n], writes n-fast -> conflict-free

    const int tid = threadIdx.x;
    const int tx  = tid & 15;      // n group
    const int ty  = tid >> 4;      // m group

    float acc[4][4] = {};

    for (int k0 = 0; k0 < KP; k0 += 16) {
        // --- stage LHS tile (64 m x 16 k), lanes vary k fastest -> coalesced 64B rows
        #pragma unroll
        for (int i = 0; i < 4; ++i) {
            int idx = tid + i * 256;
            int k   = idx & 15;
            int m   = idx >> 4;
            int p   = k0 + k;
            int kh  = p >> 8;        // tap index along the padded axis
            int ci  = p & 255;
            int row = tile_m * 64 + m + kh - 1;
            float v = (row >= 0 && row < T_) ? Xb[row * C_ + ci] : 0.0f;
            As[k][m] = v;
        }
        // --- stage RHS tile (16 k x 64 n), gather from W (L2-resident)
        #pragma unroll
        for (int i = 0; i < 4; ++i) {
            int idx = tid + i * 256;
            int n   = idx & 63;
            int kk  = idx >> 6;
            int p   = k0 + kk;
            int ci  = p & 255;
            int kf  = p >> 8;         // kh (side 0) / kw (side 1)
            int q   = tile_n * 64 + n;
            int o   = q / 3;
            int r   = q - o * 3;      // kw (side 0) / kh (side 1)
            int addr = (side == 0)
                     ? o * 4608 + ci * 9 + kf * 3 + r
                     : o * 4608 + (256 + ci) * 9 + r * 3 + kf;
            Bs[kk][n] = W[addr];
        }
        __syncthreads();

        #pragma unroll
        for (int k = 0; k < 16; ++k) {
            float a[4], bb[4];
            *(float4*)a  = *(const float4*)&As[k][ty * 4];
            *(float4*)bb = *(const float4*)&Bs[k][tx * 4];
            #pragma unroll
            for (int i = 0; i < 4; ++i)
                #pragma unroll
                for (int j = 0; j < 4; ++j)
                    acc[i][j] = fmaf(a[i], bb[j], acc[i][j]);
        }
        __syncthreads();
    }

    // --- store Y
    float* Yb = Y + (((size_t)(side * B_ + b) * T_) + (size_t)tile_m * 64) * NQ
                  + (size_t)tile_n * 64;
    #pragma unroll
    for (int i = 0; i < 4; ++i) {
        int m = ty * 4 + i;
        float4 v = make_float4(acc[i][0], acc[i][1], acc[i][2], acc[i][3]);
        *(float4*)&Yb[(size_t)m * NQ + tx * 4] = v;
    }
}

// One block per (b, o); 128 threads = t1. Shares the three B-row variants via LDS.
__global__ __launch_bounds__(128) void tc_finalize(
    const float* __restrict__ Y, const float* __restrict__ x1,
    const float* __restrict__ bias, const float* __restrict__ alpha_p,
    float* __restrict__ out)
{
    const int o = blockIdx.x & 255;
    const int b = blockIdx.x >> 8;
    const int t = threadIdx.x;   // t1 role, and t2-loader role

    __shared__ float Bs3[T_];    // all kh valid      (interior t1)
    __shared__ float BsT[T_];    // kh in {1,2}       (t1 == 0)
    __shared__ float BsB[T_];    // kh in {0,1}       (t1 == T_-1)

    const float* YB = Y + (size_t)B_ * T_ * NQ + ((size_t)b * T_ + t) * NQ + o * 3;
    float b0 = YB[0], b1 = YB[1], b2 = YB[2];   // kh = 0,1,2 at t2 = t
    Bs3[t] = b0 + b1 + b2;
    BsT[t] = b1 + b2;
    BsB[t] = b0 + b1;

    const float* YA = Y + ((size_t)b * T_ + t) * NQ + o * 3;
    float a0 = YA[0], a1 = YA[1], a2 = YA[2];   // kw = 0,1,2 at t1 = t
    float bo = bias[o];
    float A3 = bo + a0 + a1 + a2;   // interior t2
    float Al = bo + a1 + a2;        // t2 == 0
    float Ar = bo + a0 + a1;        // t2 == T_-1

    __syncthreads();

    const float* Bsel = (t == 0) ? BsT : ((t == T_ - 1) ? BsB : Bs3);

    float s = gelu_exact(Al + Bsel[0]) + gelu_exact(Ar + Bsel[T_ - 1]);
    for (int t2 = 1; t2 < T_ - 1; ++t2)
        s += gelu_exact(A3 + Bsel[t2]);

    float alpha = *alpha_p;
    size_t oi = ((size_t)b * T_ + t) * C_ + o;
    out[oi] = s * (1.0f / (float)T_) * alpha + x1[oi];
}

extern "C" void kernel_launch(void* const* d_in, const int* in_sizes, int n_in,
                              void* d_out, int out_size, void* d_ws, size_t ws_size,
                              hipStream_t stream) {
    const float* x1    = (const float*)d_in[0];
    const float* x2    = (const float*)d_in[1];
    const float* W     = (const float*)d_in[2];
    const float* bias  = (const float*)d_in[3];
    const float* alpha = (const float*)d_in[4];
    float* out = (float*)d_out;
    float* Y   = (float*)d_ws;   // [2][8][128][768] f32 = 6.3 MB

    dim3 grid(NQ / 64, T_ / 64, B_ * 2);
    tc_gemm<<<grid, 256, 0, stream>>>(x1, x2, W, Y);
    tc_finalize<<<B_ * C_, T_, 0, stream>>>(Y, x1, bias, alpha, out);
}

// Round 2
// 97.047 us; speedup vs baseline: 1.9774x; 1.9774x over previous
//
#include <hip/hip_runtime.h>
#include <math.h>

#define B_   8
#define T_   128
#define C_   256
#define KP   768    // K dim: 3 taps x 256 ci
#define NQ   768    // N dim: 256 o x 3 taps

typedef unsigned short ushort;
typedef ushort ushort4v __attribute__((ext_vector_type(4)));
typedef ushort ushort8v __attribute__((ext_vector_type(8)));
typedef __bf16 bf16x8  __attribute__((ext_vector_type(8)));
typedef float  f32x4   __attribute__((ext_vector_type(4)));

__device__ __forceinline__ ushort f2bf(float f) {
    unsigned u = __float_as_uint(f);
    u += 0x7fffu + ((u >> 16) & 1u);     // RNE
    return (ushort)(u >> 16);
}

// tanh-form gelu: x * sigmoid(1.59577x + 0.0713548x^3), max abs err ~1e-3
__device__ __forceinline__ float gelu_fast(float x) {
    float x2 = x * x;
    float y  = x * fmaf(0.0713548162726f, x2, 1.59576912161f);
    float e  = __expf(-y);
    return x * __builtin_amdgcn_rcpf(1.0f + e);
}

// ---------------------------------------------------------------------------
// Prep: build bf16 im2col LHS and transposed RHS.
// Lmat[s][b][m][p]   p = tap*256+ci ; value = x_s[b][m+tap-1][ci] (0 pad)
// Wmat[s][q][p]      q = o*3+r
//   s=0: W[o][ci][tap][r]   (tap=kh, r=kw)
//   s=1: W[o][256+ci][r][tap] (tap=kw, r=kh)
// ---------------------------------------------------------------------------
__global__ __launch_bounds__(256) void tc_pack(
    const float* __restrict__ x1, const float* __restrict__ x2,
    const float* __restrict__ W, ushort* __restrict__ Lmat,
    ushort* __restrict__ Wmat)
{
    const int bid = blockIdx.x, tid = threadIdx.x;
    if (bid < 1536) {                       // L part: 393216 chunks of 4
        int cid  = bid * 256 + tid;
        int pc   = cid % 192;               // chunk within 768-row
        int rest = cid / 192;               // (s*8+b)*128 + m
        int m    = rest & 127;
        int sb   = rest >> 7;               // s*8+b
        int tap  = pc >> 6, ci = (pc & 63) * 4;
        const float* X = (sb >= 8 ? x2 + (size_t)(sb - 8) * T_ * C_
                                  : x1 + (size_t)sb * T_ * C_);
        int row = m + tap - 1;
        float4 v = make_float4(0.f, 0.f, 0.f, 0.f);
        if (row >= 0 && row < T_) v = *(const float4*)&X[row * C_ + ci];
        ushort4v u; u.x = f2bf(v.x); u.y = f2bf(v.y); u.z = f2bf(v.z); u.w = f2bf(v.w);
        *(ushort4v*)&Lmat[(size_t)cid * 4] = u;
    } else {                                // W part: 294912 chunks of 4
        int cid  = (bid - 1536) * 256 + tid;
        int pc   = cid % 192;
        int rest = cid / 192;               // s*768 + q
        int q    = rest % 768;
        int s    = rest / 768;
        int tap  = pc >> 6, ci = (pc & 63) * 4;
        int o    = q / 3;
        int r    = q - o * 3;
        ushort4v u;
        #pragma unroll
        for (int j = 0; j < 4; ++j) {
            int cj = ci + j;
            int addr = (s == 0) ? o * 4608 + cj * 9 + tap * 3 + r
                                : o * 4608 + (256 + cj) * 9 + r * 3 + tap;
            float w = W[addr];
            ushort b = f2bf(w);
            if (j == 0) u.x = b; else if (j == 1) u.y = b; else if (j == 2) u.z = b; else u.w = b;
        }
        *(ushort4v*)&Wmat[(size_t)cid * 4] = u;
    }
}

// ---------------------------------------------------------------------------
// MFMA GEMM: Y_t[s][b][q][m] = sum_p Lmat[s][b][m][p] * Wmat[s][q][p]
// 64x64 tile, 4 waves (2x2 of 32x32), BK=32, 16x16x32 bf16 MFMA.
// LDS tiles padded to 40 bf16 stride -> 2-way (free) ds_read_b128 conflicts.
// ---------------------------------------------------------------------------
__global__ __launch_bounds__(256) void tc_mfma(
    const ushort* __restrict__ Lmat, const ushort* __restrict__ Wmat,
    float* __restrict__ Y)
{
    const int tile_n = blockIdx.x;          // 0..11
    const int tile_m = blockIdx.y;          // 0..1
    const int side   = blockIdx.z & 1;
    const int b      = blockIdx.z >> 1;

    __shared__ ushort As[64 * 40];
    __shared__ ushort Bs[64 * 40];

    const int tid = threadIdx.x;
    const int l   = tid & 63, w = tid >> 6;
    const int wr  = w >> 1,  wc = w & 1;
    const int r16 = l & 15,  kb = l >> 4;

    f32x4 acc[2][2] = {};

    const ushort* Lbase = Lmat + ((size_t)(side * B_ + b) * T_ + tile_m * 64 + (tid >> 2)) * KP + (tid & 3) * 8;
    const ushort* Wbase = Wmat + ((size_t)side * NQ + tile_n * 64 + (tid >> 2)) * KP + (tid & 3) * 8;
    const int aoff = (tid >> 2) * 40 + (tid & 3) * 8;

    const int ra = (wr * 32 + r16) * 40 + kb * 8;   // A frag i=0 (i=1: +16*40)
    const int rb = (wc * 32 + r16) * 40 + kb * 8;   // B frag j=0

    ushort8v av = *(const ushort8v*)Lbase;
    ushort8v bv = *(const ushort8v*)Wbase;

    for (int k0 = 0; k0 < KP; k0 += 32) {
        __syncthreads();                    // prior iter's frag reads done
        *(ushort8v*)&As[aoff] = av;
        *(ushort8v*)&Bs[aoff] = bv;
        __syncthreads();
        if (k0 < KP - 32) {                 // prefetch next K-tile
            av = *(const ushort8v*)(Lbase + k0 + 32);
            bv = *(const ushort8v*)(Wbase + k0 + 32);
        }
        bf16x8 a0 = __builtin_bit_cast(bf16x8, *(const ushort8v*)&As[ra]);
        bf16x8 a1 = __builtin_bit_cast(bf16x8, *(const ushort8v*)&As[ra + 16 * 40]);
        bf16x8 b0 = __builtin_bit_cast(bf16x8, *(const ushort8v*)&Bs[rb]);
        bf16x8 b1 = __builtin_bit_cast(bf16x8, *(const ushort8v*)&Bs[rb + 16 * 40]);
        acc[0][0] = __builtin_amdgcn_mfma_f32_16x16x32_bf16(a0, b0, acc[0][0], 0, 0, 0);
        acc[0][1] = __builtin_amdgcn_mfma_f32_16x16x32_bf16(a0, b1, acc[0][1], 0, 0, 0);
        acc[1][0] = __builtin_amdgcn_mfma_f32_16x16x32_bf16(a1, b0, acc[1][0], 0, 0, 0);
        acc[1][1] = __builtin_amdgcn_mfma_f32_16x16x32_bf16(a1, b1, acc[1][1], 0, 0, 0);
    }

    // Y transposed [s][b][q][m]; D layout: col(q)=l&15, row(m)=(l>>4)*4+reg
    #pragma unroll
    for (int j = 0; j < 2; ++j) {
        int gq = tile_n * 64 + wc * 32 + j * 16 + r16;
        #pragma unroll
        for (int i = 0; i < 2; ++i) {
            int gm = tile_m * 64 + wr * 32 + i * 16 + kb * 4;
            float* p = Y + ((size_t)(side * B_ + b) * NQ + gq) * T_ + gm;
            *(f32x4*)p = acc[i][j];
        }
    }
}

// ---------------------------------------------------------------------------
// Finalize: per (b,o) block, 128 threads = t1.
// s(t1) = sum_t2 gelu(A(t1, t2class) + Bsel(t1class)[t2]);
// uniform loop over all t2 with endpoint corrections.
// ---------------------------------------------------------------------------
__global__ __launch_bounds__(128) void tc_finalize(
    const float* __restrict__ Y, const float* __restrict__ x1,
    const float* __restrict__ bias, const float* __restrict__ alpha_p,
    float* __restrict__ out)
{
    const int o = blockIdx.x & 255;
    const int b = blockIdx.x >> 8;
    const int t = threadIdx.x;

    __shared__ float Bs3[T_], BsT[T_], BsB[T_];

    const float* YB = Y + ((size_t)(B_ + b) * NQ + o * 3) * T_ + t;   // side1, t=t2
    float b0 = YB[0], b1 = YB[T_], b2 = YB[2 * T_];
    Bs3[t] = b0 + b1 + b2;   // interior t1
    BsT[t] = b1 + b2;        // t1 == 0
    BsB[t] = b0 + b1;        // t1 == T-1

    const float* YA = Y + ((size_t)b * NQ + o * 3) * T_ + t;          // side0, t=t1
    float a0 = YA[0], a1 = YA[T_], a2 = YA[2 * T_];
    float bo = bias[o];
    float A3 = bo + a0 + a1 + a2;   // interior t2
    float Al = bo + a1 + a2;        // t2 == 0
    float Ar = bo + a0 + a1;        // t2 == T-1

    __syncthreads();

    const float* Bsel = (t == 0) ? BsT : ((t == T_ - 1) ? BsB : Bs3);

    float s0 = 0.f, s1 = 0.f, s2 = 0.f, s3 = 0.f;
    for (int j = 0; j < T_; j += 4) {
        s0 += gelu_fast(A3 + Bsel[j]);
        s1 += gelu_fast(A3 + Bsel[j + 1]);
        s2 += gelu_fast(A3 + Bsel[j + 2]);
        s3 += gelu_fast(A3 + Bsel[j + 3]);
    }
    float s = (s0 + s1) + (s2 + s3);
    s += gelu_fast(Al + Bsel[0])      - gelu_fast(A3 + Bsel[0]);
    s += gelu_fast(Ar + Bsel[T_ - 1]) - gelu_fast(A3 + Bsel[T_ - 1]);

    float alpha = *alpha_p;
    size_t oi = ((size_t)b * T_ + t) * C_ + o;
    out[oi] = s * (alpha * (1.0f / (float)T_)) + x1[oi];
}

extern "C" void kernel_launch(void* const* d_in, const int* in_sizes, int n_in,
                              void* d_out, int out_size, void* d_ws, size_t ws_size,
                              hipStream_t stream) {
    const float* x1    = (const float*)d_in[0];
    const float* x2    = (const float*)d_in[1];
    const float* W     = (const float*)d_in[2];
    const float* bias  = (const float*)d_in[3];
    const float* alpha = (const float*)d_in[4];
    float* out = (float*)d_out;

    // ws layout: Y_t f32 [2][8][768][128] (6.29 MB) | Lmat bf16 (3.15 MB) | Wmat bf16 (2.36 MB)
    float*  Y    = (float*)d_ws;
    ushort* Lmat = (ushort*)((char*)d_ws + (size_t)2 * B_ * NQ * T_ * 4);
    ushort* Wmat = Lmat + (size_t)2 * B_ * T_ * KP;

    tc_pack<<<1536 + 1152, 256, 0, stream>>>(x1, x2, W, Lmat, Wmat);
    tc_mfma<<<dim3(NQ / 64, T_ / 64, 2 * B_), 256, 0, stream>>>(Lmat, Wmat, Y);
    tc_finalize<<<B_ * C_, T_, 0, stream>>>(Y, x1, bias, alpha, out);
}